// Round 3
// baseline (9990.196 us; speedup 1.0000x reference)
//
#include <hip/hip_runtime.h>
#include <math.h>

#define B_ 32
#define T_ 1024
#define M_ 40

// ---------------- weight prep (transposes for coalesced access) ----------------
__global__ void prep_kernel(const float* __restrict__ W_hh, const float* __restrict__ W2,
                            const float* __restrict__ W3, const float* __restrict__ W_ih,
                            float* __restrict__ WhhT, float* __restrict__ W2t,
                            float* __restrict__ W3t, float* __restrict__ WihT4) {
  int idx = blockIdx.x * 256 + threadIdx.x;
  if (idx < 196608) {  // WhhT[k][j] = W_hh[j][k]
    int k = idx / 768, j = idx % 768;
    WhhT[idx] = W_hh[j * 256 + k];
    return;
  }
  idx -= 196608;
  if (idx < 147456) {  // W2t[tap][ci][co]
    int tap = idx >> 14, ci = (idx >> 7) & 127, co = idx & 127;
    W2t[idx] = W2[(co * 128 + ci) * 9 + tap];
    return;
  }
  idx -= 147456;
  if (idx < 147456) {  // W3t[tap][ci][co]
    int tap = idx >> 14, ci = (idx >> 7) & 127, co = idx & 127;
    W3t[idx] = W3[(co * 128 + ci) * 9 + tap];
    return;
  }
  idx -= 147456;
  if (idx < 98304) {  // WihT4[k/4][j][k%4] = W_ih[j][k] (x-part, k<128)
    int khi = idx / 3072, rem = idx % 3072, j = rem >> 2, klo = rem & 3;
    WihT4[idx] = W_ih[j * 138 + khi * 4 + klo];
  }
}

// ---------------- fused conv1+pool5 + conv2+pool4 ----------------
// grid (T/4, B), block 256.  y2: [B][T][2][128]
__global__ __launch_bounds__(256) void conv12_kernel(
    const float* __restrict__ x, const float* __restrict__ W1, const float* __restrict__ b1,
    const float* __restrict__ W2t, const float* __restrict__ b2, float* __restrict__ y2) {
  __shared__ float xt[8 * 42];          // x rows t0-2..t0+5, mel slots -1..40
  __shared__ float y1s[6 * 128 * 12];   // y1 rows t0-1..t0+4, [row][c][mslot 0..9 (=-1..8), pad]
  const int tid = threadIdx.x;
  const int t0 = blockIdx.x * 4;
  const int b = blockIdx.y;
  for (int idx = tid; idx < 8 * 42; idx += 256) {
    int row = idx / 42, slot = idx % 42;
    int t_in = t0 - 2 + row, m = slot - 1;
    float v = 0.f;
    if (t_in >= 0 && t_in < T_ && m >= 0 && m < M_) v = x[(b * T_ + t_in) * M_ + m];
    xt[idx] = v;
  }
  __syncthreads();
  const int c = tid & 127, q = tid >> 7;
  float w1[9];
#pragma unroll
  for (int i = 0; i < 9; ++i) w1[i] = W1[c * 9 + i];
  const float b1c = b1[c];
  for (int rr = 0; rr < 3; ++rr) {
    const int r = q * 3 + rr;
    const int t_in = t0 - 1 + r;
    float* yrow = &y1s[(r * 128 + c) * 12];
    if (t_in < 0 || t_in >= T_) {
#pragma unroll
      for (int s = 0; s < 12; ++s) yrow[s] = 0.f;
    } else {
      yrow[0] = 0.f; yrow[9] = 0.f; yrow[10] = 0.f; yrow[11] = 0.f;
#pragma unroll
      for (int mo = 0; mo < 8; ++mo) {
        float mx = -1e30f;
#pragma unroll
        for (int i5 = 0; i5 < 5; ++i5) {
          const int mp = mo * 5 + i5;
          float s = b1c;
#pragma unroll
          for (int dt = 0; dt < 3; ++dt)
#pragma unroll
            for (int dm = 0; dm < 3; ++dm)
              s += xt[(r + dt) * 42 + mp + dm] * w1[dt * 3 + dm];
          mx = fmaxf(mx, s);
        }
        yrow[1 + mo] = fmaxf(mx, 0.f);  // relu after (pool of conv+b); relu monotone
      }
    }
  }
  __syncthreads();
  // conv2: thread (co, tq) computes 2 t x 8 m outputs
  const int co = c, tq = q;
  float acc[2][8];
#pragma unroll
  for (int tl = 0; tl < 2; ++tl)
#pragma unroll
    for (int mo = 0; mo < 8; ++mo) acc[tl][mo] = 0.f;
  for (int ci = 0; ci < 128; ++ci) {
    float w[9];
#pragma unroll
    for (int i = 0; i < 9; ++i) w[i] = W2t[i * 16384 + ci * 128 + co];
    float xv[4][10];
#pragma unroll
    for (int rr = 0; rr < 4; ++rr) {
      const float* p = &y1s[((2 * tq + rr) * 128 + ci) * 12];
      const float4 a = *(const float4*)p;
      const float4 bq = *(const float4*)(p + 4);
      const float2 cq = *(const float2*)(p + 8);
      xv[rr][0] = a.x; xv[rr][1] = a.y; xv[rr][2] = a.z; xv[rr][3] = a.w;
      xv[rr][4] = bq.x; xv[rr][5] = bq.y; xv[rr][6] = bq.z; xv[rr][7] = bq.w;
      xv[rr][8] = cq.x; xv[rr][9] = cq.y;
    }
#pragma unroll
    for (int dt = 0; dt < 3; ++dt)
#pragma unroll
      for (int dm = 0; dm < 3; ++dm) {
        const float wv = w[dt * 3 + dm];
#pragma unroll
        for (int tl = 0; tl < 2; ++tl)
#pragma unroll
          for (int mo = 0; mo < 8; ++mo)
            acc[tl][mo] += xv[tl + dt][mo + dm] * wv;
      }
  }
  const float b2c = b2[co];
#pragma unroll
  for (int tl = 0; tl < 2; ++tl) {
    const int t = t0 + 2 * tq + tl;
    float m0 = fmaxf(fmaxf(acc[tl][0], acc[tl][1]), fmaxf(acc[tl][2], acc[tl][3])) + b2c;
    float m1 = fmaxf(fmaxf(acc[tl][4], acc[tl][5]), fmaxf(acc[tl][6], acc[tl][7])) + b2c;
    y2[((b * T_ + t) * 2 + 0) * 128 + co] = fmaxf(m0, 0.f);
    y2[((b * T_ + t) * 2 + 1) * 128 + co] = fmaxf(m1, 0.f);
  }
}

// ---------------- conv3+pool2 -> feats [T][B][128] ----------------
__global__ __launch_bounds__(256) void conv3_kernel(
    const float* __restrict__ y2, const float* __restrict__ W3t, const float* __restrict__ b3,
    float* __restrict__ feats) {
  __shared__ float y2s[6 * 128 * 4];  // [row][ci][mslot 0..3 (=-1..2)]
  const int tid = threadIdx.x;
  const int t0 = blockIdx.x * 4;
  const int b = blockIdx.y;
  for (int idx = tid; idx < 768; idx += 256) {
    int row = idx / 128, ci = idx % 128;
    y2s[(row * 128 + ci) * 4 + 0] = 0.f;
    y2s[(row * 128 + ci) * 4 + 3] = 0.f;
  }
  for (int idx = tid; idx < 6 * 256; idx += 256) {
    int row = idx / 256, rem = idx % 256;
    int m = rem >> 7, ci = rem & 127;
    int t_in = t0 - 1 + row;
    float v = 0.f;
    if (t_in >= 0 && t_in < T_) v = y2[((b * T_ + t_in) * 2 + m) * 128 + ci];
    y2s[(row * 128 + ci) * 4 + 1 + m] = v;
  }
  __syncthreads();
  const int co = tid & 127, tq = tid >> 7;
  float acc[2][2] = {{0.f, 0.f}, {0.f, 0.f}};
  for (int ci = 0; ci < 128; ++ci) {
    float w[9];
#pragma unroll
    for (int i = 0; i < 9; ++i) w[i] = W3t[i * 16384 + ci * 128 + co];
    float4 xr[4];
#pragma unroll
    for (int rr = 0; rr < 4; ++rr)
      xr[rr] = *(const float4*)&y2s[((2 * tq + rr) * 128 + ci) * 4];
#pragma unroll
    for (int dt = 0; dt < 3; ++dt)
#pragma unroll
      for (int tl = 0; tl < 2; ++tl) {
        const float4 v = xr[tl + dt];
        acc[tl][0] += v.y * w[dt * 3 + 1] + v.z * w[dt * 3 + 2];  // m=0: taps dm=1,2
        acc[tl][1] += v.y * w[dt * 3 + 0] + v.z * w[dt * 3 + 1];  // m=1: taps dm=0,1
      }
  }
  const float b3c = b3[co];
#pragma unroll
  for (int tl = 0; tl < 2; ++tl) {
    const int t = t0 + 2 * tq + tl;
    float f = fmaxf(fmaxf(acc[tl][0], acc[tl][1]) + b3c, 0.f);
    feats[(t * B_ + b) * 128 + co] = f;
  }
}

// ---------------- gi_x = feats @ W_ih_x^T + b_ih -> [T*B][768] ----------------
__global__ __launch_bounds__(256) void gid_kernel(
    const float* __restrict__ feats, const float* __restrict__ WihT4,
    const float* __restrict__ b_ih, float* __restrict__ gi) {
  __shared__ float fs[32 * 128];
  const int tid = threadIdx.x;
  const int jb = blockIdx.x;  // 0..2
  const int rb = blockIdx.y;  // 0..1023
  const float4* src = (const float4*)(feats + rb * 32 * 128);
  float4* dst = (float4*)fs;
  for (int i = tid; i < 1024; i += 256) dst[i] = src[i];
  __syncthreads();
  const int j = jb * 256 + tid;
  float acc[32];
#pragma unroll
  for (int r = 0; r < 32; ++r) acc[r] = 0.f;
  for (int k4 = 0; k4 < 32; ++k4) {
    const float4 w4 = *(const float4*)&WihT4[(k4 * 768 + j) * 4];
#pragma unroll
    for (int r = 0; r < 32; ++r) {
      const float4 f4 = *(const float4*)&fs[r * 128 + k4 * 4];
      acc[r] += f4.x * w4.x + f4.y * w4.y + f4.z * w4.z + f4.w * w4.w;
    }
  }
  const float bj = b_ih[j];
  for (int r = 0; r < 32; ++r) gi[(rb * 32 + r) * 768 + j] = acc[r] + bj;
}

// ---------------- persistent GRU: 32 blocks (one batch each), 768 threads ----------------
__global__ __launch_bounds__(768) void rnn_kernel(
    const float* __restrict__ gi, const float* __restrict__ WhhT,
    const float* __restrict__ W_ih, const float* __restrict__ b_hh,
    const float* __restrict__ Wf, const float* __restrict__ bf,
    const float* __restrict__ targets, const int* __restrict__ force_mask,
    float* __restrict__ out) {
  __shared__ float h_s[256];
  __shared__ float tf_s[16];
  __shared__ float gis[768];
  __shared__ float part[4 * 768];
  __shared__ float wtf[10 * 768];
  __shared__ float wfs[10 * 256];
  __shared__ float bhh_s[768];
  __shared__ float bf_s[16];
  const int tid = threadIdx.x;
  const int b = blockIdx.x;
  for (int idx = tid; idx < 7680; idx += 768) {
    int cc = idx / 768, j = idx % 768;
    wtf[idx] = W_ih[j * 138 + 128 + cc];
  }
  for (int idx = tid; idx < 2560; idx += 768) wfs[idx] = Wf[idx];
  bhh_s[tid] = b_hh[tid];
  if (tid < 256) h_s[tid] = 0.f;
  if (tid < 10) { tf_s[tid] = 0.f; bf_s[tid] = bf[tid]; }
  __syncthreads();
  const int ks = tid / 192;   // k-slice 0..3 (wave-uniform)
  const int jq = tid % 192;   // j-quad
  const float* wbase = WhhT + (ks * 64) * 768 + jq * 4;
  for (int t = 0; t < T_; ++t) {
    // gi row + teacher-forcing contribution
    float giv = gi[(t * B_ + b) * 768 + tid];
#pragma unroll
    for (int cc = 0; cc < 10; ++cc) giv += wtf[cc * 768 + tid] * tf_s[cc];
    // partial gh matvec: 4 j-columns x 64 k
    float4 a4 = make_float4(0.f, 0.f, 0.f, 0.f);
    const float* wp = wbase;
#pragma unroll 4
    for (int kk4 = 0; kk4 < 16; ++kk4) {
      const float4 h4 = *(const float4*)&h_s[ks * 64 + kk4 * 4];
      const float4 w0 = *(const float4*)(wp);
      const float4 w1v = *(const float4*)(wp + 768);
      const float4 w2v = *(const float4*)(wp + 1536);
      const float4 w3v = *(const float4*)(wp + 2304);
      a4.x += w0.x * h4.x + w1v.x * h4.y + w2v.x * h4.z + w3v.x * h4.w;
      a4.y += w0.y * h4.x + w1v.y * h4.y + w2v.y * h4.z + w3v.y * h4.w;
      a4.z += w0.z * h4.x + w1v.z * h4.y + w2v.z * h4.z + w3v.z * h4.w;
      a4.w += w0.w * h4.x + w1v.w * h4.y + w2v.w * h4.z + w3v.w * h4.w;
      wp += 4 * 768;
    }
    *(float4*)&part[ks * 768 + jq * 4] = a4;
    gis[tid] = giv;
    __syncthreads();
    if (tid < 256) {
      const int j = tid;
      float ghr = bhh_s[j] + part[j] + part[768 + j] + part[1536 + j] + part[2304 + j];
      float ghz = bhh_s[256 + j] + part[256 + j] + part[1024 + j] + part[1792 + j] + part[2560 + j];
      float ghn = bhh_s[512 + j] + part[512 + j] + part[1280 + j] + part[2048 + j] + part[2816 + j];
      const float r = 1.f / (1.f + expf(-(gis[j] + ghr)));
      const float z = 1.f / (1.f + expf(-(gis[256 + j] + ghz)));
      const float n = tanhf(gis[512 + j] + r * ghn);
      h_s[j] = (1.f - z) * n + z * h_s[j];
    }
    __syncthreads();
    if (tid < 64) {
      const float h0 = h_s[tid], h1 = h_s[tid + 64], h2 = h_s[tid + 128], h3 = h_s[tid + 192];
      float p[10];
#pragma unroll
      for (int cc = 0; cc < 10; ++cc)
        p[cc] = wfs[cc * 256 + tid] * h0 + wfs[cc * 256 + tid + 64] * h1 +
                wfs[cc * 256 + tid + 128] * h2 + wfs[cc * 256 + tid + 192] * h3;
#pragma unroll
      for (int off = 32; off > 0; off >>= 1)
#pragma unroll
        for (int cc = 0; cc < 10; ++cc) p[cc] += __shfl_xor(p[cc], off);
      if (tid == 0) {
        const int fm = force_mask[t * B_ + b];
#pragma unroll
        for (int cc = 0; cc < 10; ++cc) {
          const float o = p[cc] + bf_s[cc];
          out[(b * T_ + t) * 10 + cc] = o;
          tf_s[cc] = (fm > 0) ? targets[(b * T_ + t) * 10 + cc] : (o > 0.f ? 1.f : 0.f);
        }
      }
    }
    __syncthreads();
  }
}

extern "C" void kernel_launch(void* const* d_in, const int* in_sizes, int n_in,
                              void* d_out, int out_size, void* d_ws, size_t ws_size,
                              hipStream_t stream) {
  const float* x = (const float*)d_in[0];
  const float* targets = (const float*)d_in[1];
  const int* fmask = (const int*)d_in[2];
  const float* W1 = (const float*)d_in[3];
  const float* b1 = (const float*)d_in[4];
  const float* W2 = (const float*)d_in[5];
  const float* b2 = (const float*)d_in[6];
  const float* W3 = (const float*)d_in[7];
  const float* b3 = (const float*)d_in[8];
  const float* Wih = (const float*)d_in[9];
  const float* Whh = (const float*)d_in[10];
  const float* bih = (const float*)d_in[11];
  const float* bhh = (const float*)d_in[12];
  const float* Wf = (const float*)d_in[13];
  const float* bf = (const float*)d_in[14];
  float* out = (float*)d_out;
  float* ws = (float*)d_ws;
  // workspace layout (floats), peak 29,949,952 (~114.25 MiB).
  // y2 ALIASES the gi region: y2 is dead after conv3_kernel, gi is written
  // only afterwards (gid_kernel) — stream-ordered, so the overlap is safe.
  float* WhhT = ws;                 // 196608
  float* W2t = ws + 196608;         // 147456
  float* W3t = ws + 344064;         // 147456
  float* WihT4 = ws + 491520;       // 98304
  float* feats = ws + 589824;       // 4194304
  float* gi = ws + 4784128;         // 25165824
  float* y2 = gi;                   // 8388608 (alias, dead before gi written)

  prep_kernel<<<2304, 256, 0, stream>>>(Whh, W2, W3, Wih, WhhT, W2t, W3t, WihT4);
  conv12_kernel<<<dim3(256, 32), 256, 0, stream>>>(x, W1, b1, W2t, b2, y2);
  conv3_kernel<<<dim3(256, 32), 256, 0, stream>>>(y2, W3t, b3, feats);
  gid_kernel<<<dim3(3, 1024), 256, 0, stream>>>(feats, WihT4, bih, gi);
  rnn_kernel<<<32, 768, 0, stream>>>(gi, WhhT, Wih, bhh, Wf, bf, targets, fmask, out);
}

// Round 4
// 9706.136 us; speedup vs baseline: 1.0293x; 1.0293x over previous
//
#include <hip/hip_runtime.h>
#include <math.h>

#define B_ 32
#define T_ 1024
#define M_ 40

// ---------------- weight prep (transposes for coalesced access) ----------------
__global__ void prep_kernel(const float* __restrict__ W2, const float* __restrict__ W3,
                            const float* __restrict__ W_ih, float* __restrict__ W2t,
                            float* __restrict__ W3t, float* __restrict__ WihT4) {
  int idx = blockIdx.x * 256 + threadIdx.x;
  if (idx < 147456) {  // W2t[tap][ci][co]
    int tap = idx >> 14, ci = (idx >> 7) & 127, co = idx & 127;
    W2t[idx] = W2[(co * 128 + ci) * 9 + tap];
    return;
  }
  idx -= 147456;
  if (idx < 147456) {  // W3t[tap][ci][co]
    int tap = idx >> 14, ci = (idx >> 7) & 127, co = idx & 127;
    W3t[idx] = W3[(co * 128 + ci) * 9 + tap];
    return;
  }
  idx -= 147456;
  if (idx < 98304) {  // WihT4[k/4][j][k%4] = W_ih[j][k] (x-part, k<128)
    int khi = idx / 3072, rem = idx % 3072, j = rem >> 2, klo = rem & 3;
    WihT4[idx] = W_ih[j * 138 + khi * 4 + klo];
  }
}

// ---------------- fused conv1+pool5 + conv2+pool4 ----------------
// grid (T/4, B), block 256.  y2: [B][T][2][128]
__global__ __launch_bounds__(256) void conv12_kernel(
    const float* __restrict__ x, const float* __restrict__ W1, const float* __restrict__ b1,
    const float* __restrict__ W2t, const float* __restrict__ b2, float* __restrict__ y2) {
  __shared__ float xt[8 * 42];          // x rows t0-2..t0+5, mel slots -1..40
  __shared__ float y1s[6 * 128 * 12];   // y1 rows t0-1..t0+4, [row][c][mslot 0..9 (=-1..8), pad]
  const int tid = threadIdx.x;
  const int t0 = blockIdx.x * 4;
  const int b = blockIdx.y;
  for (int idx = tid; idx < 8 * 42; idx += 256) {
    int row = idx / 42, slot = idx % 42;
    int t_in = t0 - 2 + row, m = slot - 1;
    float v = 0.f;
    if (t_in >= 0 && t_in < T_ && m >= 0 && m < M_) v = x[(b * T_ + t_in) * M_ + m];
    xt[idx] = v;
  }
  __syncthreads();
  const int c = tid & 127, q = tid >> 7;
  float w1[9];
#pragma unroll
  for (int i = 0; i < 9; ++i) w1[i] = W1[c * 9 + i];
  const float b1c = b1[c];
  for (int rr = 0; rr < 3; ++rr) {
    const int r = q * 3 + rr;
    const int t_in = t0 - 1 + r;
    float* yrow = &y1s[(r * 128 + c) * 12];
    if (t_in < 0 || t_in >= T_) {
#pragma unroll
      for (int s = 0; s < 12; ++s) yrow[s] = 0.f;
    } else {
      yrow[0] = 0.f; yrow[9] = 0.f; yrow[10] = 0.f; yrow[11] = 0.f;
#pragma unroll
      for (int mo = 0; mo < 8; ++mo) {
        float mx = -1e30f;
#pragma unroll
        for (int i5 = 0; i5 < 5; ++i5) {
          const int mp = mo * 5 + i5;
          float s = b1c;
#pragma unroll
          for (int dt = 0; dt < 3; ++dt)
#pragma unroll
            for (int dm = 0; dm < 3; ++dm)
              s += xt[(r + dt) * 42 + mp + dm] * w1[dt * 3 + dm];
          mx = fmaxf(mx, s);
        }
        yrow[1 + mo] = fmaxf(mx, 0.f);  // relu after (pool of conv+b); relu monotone
      }
    }
  }
  __syncthreads();
  // conv2: thread (co, tq) computes 2 t x 8 m outputs
  const int co = c, tq = q;
  float acc[2][8];
#pragma unroll
  for (int tl = 0; tl < 2; ++tl)
#pragma unroll
    for (int mo = 0; mo < 8; ++mo) acc[tl][mo] = 0.f;
  for (int ci = 0; ci < 128; ++ci) {
    float w[9];
#pragma unroll
    for (int i = 0; i < 9; ++i) w[i] = W2t[i * 16384 + ci * 128 + co];
    float xv[4][10];
#pragma unroll
    for (int rr = 0; rr < 4; ++rr) {
      const float* p = &y1s[((2 * tq + rr) * 128 + ci) * 12];
      const float4 a = *(const float4*)p;
      const float4 bq = *(const float4*)(p + 4);
      const float2 cq = *(const float2*)(p + 8);
      xv[rr][0] = a.x; xv[rr][1] = a.y; xv[rr][2] = a.z; xv[rr][3] = a.w;
      xv[rr][4] = bq.x; xv[rr][5] = bq.y; xv[rr][6] = bq.z; xv[rr][7] = bq.w;
      xv[rr][8] = cq.x; xv[rr][9] = cq.y;
    }
#pragma unroll
    for (int dt = 0; dt < 3; ++dt)
#pragma unroll
      for (int dm = 0; dm < 3; ++dm) {
        const float wv = w[dt * 3 + dm];
#pragma unroll
        for (int tl = 0; tl < 2; ++tl)
#pragma unroll
          for (int mo = 0; mo < 8; ++mo)
            acc[tl][mo] += xv[tl + dt][mo + dm] * wv;
      }
  }
  const float b2c = b2[co];
#pragma unroll
  for (int tl = 0; tl < 2; ++tl) {
    const int t = t0 + 2 * tq + tl;
    float m0 = fmaxf(fmaxf(acc[tl][0], acc[tl][1]), fmaxf(acc[tl][2], acc[tl][3])) + b2c;
    float m1 = fmaxf(fmaxf(acc[tl][4], acc[tl][5]), fmaxf(acc[tl][6], acc[tl][7])) + b2c;
    y2[((b * T_ + t) * 2 + 0) * 128 + co] = fmaxf(m0, 0.f);
    y2[((b * T_ + t) * 2 + 1) * 128 + co] = fmaxf(m1, 0.f);
  }
}

// ---------------- conv3+pool2 -> feats [T][B][128] ----------------
__global__ __launch_bounds__(256) void conv3_kernel(
    const float* __restrict__ y2, const float* __restrict__ W3t, const float* __restrict__ b3,
    float* __restrict__ feats) {
  __shared__ float y2s[6 * 128 * 4];  // [row][ci][mslot 0..3 (=-1..2)]
  const int tid = threadIdx.x;
  const int t0 = blockIdx.x * 4;
  const int b = blockIdx.y;
  for (int idx = tid; idx < 768; idx += 256) {
    int row = idx / 128, ci = idx % 128;
    y2s[(row * 128 + ci) * 4 + 0] = 0.f;
    y2s[(row * 128 + ci) * 4 + 3] = 0.f;
  }
  for (int idx = tid; idx < 6 * 256; idx += 256) {
    int row = idx / 256, rem = idx % 256;
    int m = rem >> 7, ci = rem & 127;
    int t_in = t0 - 1 + row;
    float v = 0.f;
    if (t_in >= 0 && t_in < T_) v = y2[((b * T_ + t_in) * 2 + m) * 128 + ci];
    y2s[(row * 128 + ci) * 4 + 1 + m] = v;
  }
  __syncthreads();
  const int co = tid & 127, tq = tid >> 7;
  float acc[2][2] = {{0.f, 0.f}, {0.f, 0.f}};
  for (int ci = 0; ci < 128; ++ci) {
    float w[9];
#pragma unroll
    for (int i = 0; i < 9; ++i) w[i] = W3t[i * 16384 + ci * 128 + co];
    float4 xr[4];
#pragma unroll
    for (int rr = 0; rr < 4; ++rr)
      xr[rr] = *(const float4*)&y2s[((2 * tq + rr) * 128 + ci) * 4];
#pragma unroll
    for (int dt = 0; dt < 3; ++dt)
#pragma unroll
      for (int tl = 0; tl < 2; ++tl) {
        const float4 v = xr[tl + dt];
        acc[tl][0] += v.y * w[dt * 3 + 1] + v.z * w[dt * 3 + 2];  // m=0: taps dm=1,2
        acc[tl][1] += v.y * w[dt * 3 + 0] + v.z * w[dt * 3 + 1];  // m=1: taps dm=0,1
      }
  }
  const float b3c = b3[co];
#pragma unroll
  for (int tl = 0; tl < 2; ++tl) {
    const int t = t0 + 2 * tq + tl;
    float f = fmaxf(fmaxf(acc[tl][0], acc[tl][1]) + b3c, 0.f);
    feats[(t * B_ + b) * 128 + co] = f;
  }
}

// ---------------- gi_x = feats @ W_ih_x^T + b_ih -> [T*B][768] ----------------
__global__ __launch_bounds__(256) void gid_kernel(
    const float* __restrict__ feats, const float* __restrict__ WihT4,
    const float* __restrict__ b_ih, float* __restrict__ gi) {
  __shared__ float fs[32 * 128];
  const int tid = threadIdx.x;
  const int jb = blockIdx.x;  // 0..2
  const int rb = blockIdx.y;  // 0..1023
  const float4* src = (const float4*)(feats + rb * 32 * 128);
  float4* dst = (float4*)fs;
  for (int i = tid; i < 1024; i += 256) dst[i] = src[i];
  __syncthreads();
  const int j = jb * 256 + tid;
  float acc[32];
#pragma unroll
  for (int r = 0; r < 32; ++r) acc[r] = 0.f;
  for (int k4 = 0; k4 < 32; ++k4) {
    const float4 w4 = *(const float4*)&WihT4[(k4 * 768 + j) * 4];
#pragma unroll
    for (int r = 0; r < 32; ++r) {
      const float4 f4 = *(const float4*)&fs[r * 128 + k4 * 4];
      acc[r] += f4.x * w4.x + f4.y * w4.y + f4.z * w4.z + f4.w * w4.w;
    }
  }
  const float bj = b_ih[j];
  for (int r = 0; r < 32; ++r) gi[(rb * 32 + r) * 768 + j] = acc[r] + bj;
}

// ---------------- cooperative GRU: 256 blocks = 32 batches x 8 h-slices ----------------
// Each block owns h-slice s (32 h elems) and its 96 gate-rows of W_hh, LDS-resident.
// Per step: LDS matvec -> gates -> store h slice -> global barrier (monotonic counter,
// release/acquire, agent scope) -> read full h (double-buffered) -> redundant out/tf.
__global__ __launch_bounds__(256, 1) void rnn_kernel(
    const float* __restrict__ gi, const float* __restrict__ W_hh,
    const float* __restrict__ W_ih, const float* __restrict__ b_hh,
    const float* __restrict__ Wf, const float* __restrict__ bf,
    const float* __restrict__ targets, const int* __restrict__ force_mask,
    float* __restrict__ out, float* __restrict__ hb, unsigned int* __restrict__ bar) {
  __shared__ __align__(16) float Wl[96 * 260];   // rows 0..31=r, 32..63=z, 64..95=n; stride 260
  __shared__ __align__(16) float h_loc[256];
  __shared__ float part[192];
  __shared__ float gis2[96];
  __shared__ float wtfl[960];       // [cc][row]
  __shared__ float wfs[2560];       // [cc][k]
  __shared__ float bhh_l[96];
  __shared__ float bf_s[16];
  __shared__ float tf_s[16];
  const int tid = threadIdx.x;
  const int b = blockIdx.x >> 3;
  const int s = blockIdx.x & 7;
  // load W slice (coalesced), teacher-forcing cols, Wf, biases
  for (int idx = tid; idx < 96 * 256; idx += 256) {
    const int row = idx >> 8, k = idx & 255;
    const int j = (row >> 5) * 256 + s * 32 + (row & 31);
    Wl[row * 260 + k] = W_hh[j * 256 + k];
  }
  for (int idx = tid; idx < 960; idx += 256) {
    const int cc = idx / 96, row = idx % 96;
    const int j = (row >> 5) * 256 + s * 32 + (row & 31);
    wtfl[idx] = W_ih[j * 138 + 128 + cc];
  }
  for (int idx = tid; idx < 2560; idx += 256) wfs[idx] = Wf[idx];
  if (tid < 96) {
    const int j = (tid >> 5) * 256 + s * 32 + (tid & 31);
    bhh_l[tid] = b_hh[j];
  }
  h_loc[tid] = 0.f;
  if (tid < 10) { tf_s[tid] = 0.f; bf_s[tid] = bf[tid]; }
  __syncthreads();

  const int r_id = tid >> 1, half = tid & 1;
  const float* wrow = &Wl[r_id * 260 + half * 128];
  const float* hhalf = &h_loc[half * 128];
  unsigned int* barp = &bar[b * 16];

  for (int t = 0; t < T_; ++t) {
    // prefetch (latency hidden behind matvec)
    float giv = 0.f;
    if (tid < 96) {
      const int j = (tid >> 5) * 256 + s * 32 + (tid & 31);
      giv = gi[(t * B_ + b) * 768 + j];
    }
    int fm = 0;
    float tg[10];
    if (tid == 0) {
      fm = force_mask[t * B_ + b];
#pragma unroll
      for (int cc = 0; cc < 10; ++cc) tg[cc] = targets[(b * T_ + t) * 10 + cc];
    }
    // LDS matvec: thread (row, half) does 128 MACs
    if (tid < 192) {
      float4 a4 = make_float4(0.f, 0.f, 0.f, 0.f);
#pragma unroll 8
      for (int kk = 0; kk < 32; ++kk) {
        const float4 w4 = *(const float4*)(wrow + 4 * kk);
        const float4 h4 = *(const float4*)(hhalf + 4 * kk);
        a4.x += w4.x * h4.x; a4.y += w4.y * h4.y;
        a4.z += w4.z * h4.z; a4.w += w4.w * h4.w;
      }
      part[tid] = a4.x + a4.y + a4.z + a4.w;
    }
    if (tid < 96) {
      float tadd = 0.f;
#pragma unroll
      for (int cc = 0; cc < 10; ++cc) tadd += wtfl[cc * 96 + tid] * tf_s[cc];
      gis2[tid] = giv + tadd;
    }
    __syncthreads();  // S1: part, gis2 ready
    const int p = t & 1;
    if (tid < 32) {
      const float ghr = part[2 * tid] + part[2 * tid + 1] + bhh_l[tid];
      const float ghz = part[64 + 2 * tid] + part[65 + 2 * tid] + bhh_l[32 + tid];
      const float ghn = part[128 + 2 * tid] + part[129 + 2 * tid] + bhh_l[64 + tid];
      const float r = 1.f / (1.f + expf(-(gis2[tid] + ghr)));
      const float z = 1.f / (1.f + expf(-(gis2[32 + tid] + ghz)));
      const float n = tanhf(gis2[64 + tid] + r * ghn);
      const float hn = (1.f - z) * n + z * h_loc[s * 32 + tid];
      __hip_atomic_store(&hb[(p * B_ + b) * 256 + s * 32 + tid], hn,
                         __ATOMIC_RELAXED, __HIP_MEMORY_SCOPE_AGENT);
    }
    __syncthreads();  // S2: slice stored before arrival
    if (tid == 0) {
      __hip_atomic_fetch_add(barp, 1u, __ATOMIC_RELEASE, __HIP_MEMORY_SCOPE_AGENT);
      const unsigned int target = 8u * (unsigned int)(t + 1);
      while (__hip_atomic_load(barp, __ATOMIC_ACQUIRE, __HIP_MEMORY_SCOPE_AGENT) < target) {
        __builtin_amdgcn_s_sleep(2);
      }
    }
    __syncthreads();  // S3: all 8 blocks' h visible
    h_loc[tid] = __hip_atomic_load(&hb[(p * B_ + b) * 256 + tid],
                                   __ATOMIC_RELAXED, __HIP_MEMORY_SCOPE_AGENT);
    __syncthreads();  // S4: h_loc ready
    // redundant out/tf (deterministic -> identical across the 8 blocks)
    float pr[10];
    if (tid < 64) {
      const float h0 = h_loc[tid], h1 = h_loc[tid + 64], h2 = h_loc[tid + 128],
                  h3 = h_loc[tid + 192];
#pragma unroll
      for (int cc = 0; cc < 10; ++cc)
        pr[cc] = wfs[cc * 256 + tid] * h0 + wfs[cc * 256 + tid + 64] * h1 +
                 wfs[cc * 256 + tid + 128] * h2 + wfs[cc * 256 + tid + 192] * h3;
#pragma unroll
      for (int off = 32; off > 0; off >>= 1)
#pragma unroll
        for (int cc = 0; cc < 10; ++cc) pr[cc] += __shfl_xor(pr[cc], off);
    }
    if (tid == 0) {
#pragma unroll
      for (int cc = 0; cc < 10; ++cc) {
        const float o = pr[cc] + bf_s[cc];
        if (s == 0) out[(b * T_ + t) * 10 + cc] = o;
        tf_s[cc] = (fm > 0) ? tg[cc] : (o > 0.f ? 1.f : 0.f);
      }
    }
    __syncthreads();  // S5: tf_s ready for next step
  }
}

extern "C" void kernel_launch(void* const* d_in, const int* in_sizes, int n_in,
                              void* d_out, int out_size, void* d_ws, size_t ws_size,
                              hipStream_t stream) {
  const float* x = (const float*)d_in[0];
  const float* targets = (const float*)d_in[1];
  const int* fmask = (const int*)d_in[2];
  const float* W1 = (const float*)d_in[3];
  const float* b1 = (const float*)d_in[4];
  const float* W2 = (const float*)d_in[5];
  const float* b2 = (const float*)d_in[6];
  const float* W3 = (const float*)d_in[7];
  const float* b3 = (const float*)d_in[8];
  const float* Wih = (const float*)d_in[9];
  const float* Whh = (const float*)d_in[10];
  const float* bih = (const float*)d_in[11];
  const float* bhh = (const float*)d_in[12];
  const float* Wf = (const float*)d_in[13];
  const float* bf = (const float*)d_in[14];
  float* out = (float*)d_out;
  float* ws = (float*)d_ws;
  // workspace layout (floats), peak ~113.6 MiB. y2 aliases gi (y2 dead before gi written).
  unsigned int* bar = (unsigned int*)ws;  // 512 uints (32 counters, 64B apart)
  float* hb = ws + 512;                   // 16384 (2 parities x 32 b x 256)
  float* W2t = ws + 16896;                // 147456
  float* W3t = ws + 164352;               // 147456
  float* WihT4 = ws + 311808;             // 98304
  float* feats = ws + 410112;             // 4194304
  float* gi = ws + 4604416;               // 25165824
  float* y2 = gi;                         // 8388608 (alias)

  prep_kernel<<<1536, 256, 0, stream>>>(W2, W3, Wih, W2t, W3t, WihT4);
  hipMemsetAsync(bar, 0, 512 * sizeof(unsigned int), stream);
  conv12_kernel<<<dim3(256, 32), 256, 0, stream>>>(x, W1, b1, W2t, b2, y2);
  conv3_kernel<<<dim3(256, 32), 256, 0, stream>>>(y2, W3t, b3, feats);
  gid_kernel<<<dim3(3, 1024), 256, 0, stream>>>(feats, WihT4, bih, gi);
  void* args[] = {&gi, &Whh, &Wih, &bhh, &Wf, &bf, &targets, &fmask, &out, &hb, &bar};
  hipLaunchCooperativeKernel((const void*)rnn_kernel, dim3(256), dim3(256), args, 0, stream);
}

// Round 8
// 8001.019 us; speedup vs baseline: 1.2486x; 1.2131x over previous
//
#include <hip/hip_runtime.h>
#include <math.h>

#define B_ 32
#define T_ 1024
#define M_ 40

// ---------------- weight prep (transposes for coalesced access) ----------------
__global__ void prep_kernel(const float* __restrict__ W_hh, const float* __restrict__ W2,
                            const float* __restrict__ W3, const float* __restrict__ W_ih,
                            float* __restrict__ WhhT, float* __restrict__ W2t,
                            float* __restrict__ W3t, float* __restrict__ WihT4) {
  int idx = blockIdx.x * 256 + threadIdx.x;
  if (idx < 196608) {  // WhhT[k][j] = W_hh[j][k]
    int k = idx / 768, j = idx % 768;
    WhhT[idx] = W_hh[j * 256 + k];
    return;
  }
  idx -= 196608;
  if (idx < 147456) {  // W2t[tap][ci][co]
    int tap = idx >> 14, ci = (idx >> 7) & 127, co = idx & 127;
    W2t[idx] = W2[(co * 128 + ci) * 9 + tap];
    return;
  }
  idx -= 147456;
  if (idx < 147456) {  // W3t[tap][ci][co]
    int tap = idx >> 14, ci = (idx >> 7) & 127, co = idx & 127;
    W3t[idx] = W3[(co * 128 + ci) * 9 + tap];
    return;
  }
  idx -= 147456;
  if (idx < 98304) {  // WihT4[k/4][j][k%4] = W_ih[j][k] (x-part, k<128)
    int khi = idx / 3072, rem = idx % 3072, j = rem >> 2, klo = rem & 3;
    WihT4[idx] = W_ih[j * 138 + khi * 4 + klo];
  }
}

// ---------------- fused conv1+pool5 + conv2+pool4 ----------------
// grid (T/4, B), block 256.  y2: [B][T][2][128]
__global__ __launch_bounds__(256) void conv12_kernel(
    const float* __restrict__ x, const float* __restrict__ W1, const float* __restrict__ b1,
    const float* __restrict__ W2t, const float* __restrict__ b2, float* __restrict__ y2) {
  __shared__ float xt[8 * 42];          // x rows t0-2..t0+5, mel slots -1..40
  __shared__ float y1s[6 * 128 * 12];   // y1 rows t0-1..t0+4, [row][c][mslot 0..9 (=-1..8), pad]
  const int tid = threadIdx.x;
  const int t0 = blockIdx.x * 4;
  const int b = blockIdx.y;
  for (int idx = tid; idx < 8 * 42; idx += 256) {
    int row = idx / 42, slot = idx % 42;
    int t_in = t0 - 2 + row, m = slot - 1;
    float v = 0.f;
    if (t_in >= 0 && t_in < T_ && m >= 0 && m < M_) v = x[(b * T_ + t_in) * M_ + m];
    xt[idx] = v;
  }
  __syncthreads();
  const int c = tid & 127, q = tid >> 7;
  float w1[9];
#pragma unroll
  for (int i = 0; i < 9; ++i) w1[i] = W1[c * 9 + i];
  const float b1c = b1[c];
  for (int rr = 0; rr < 3; ++rr) {
    const int r = q * 3 + rr;
    const int t_in = t0 - 1 + r;
    float* yrow = &y1s[(r * 128 + c) * 12];
    if (t_in < 0 || t_in >= T_) {
#pragma unroll
      for (int s = 0; s < 12; ++s) yrow[s] = 0.f;
    } else {
      yrow[0] = 0.f; yrow[9] = 0.f; yrow[10] = 0.f; yrow[11] = 0.f;
#pragma unroll
      for (int mo = 0; mo < 8; ++mo) {
        float mx = -1e30f;
#pragma unroll
        for (int i5 = 0; i5 < 5; ++i5) {
          const int mp = mo * 5 + i5;
          float s = b1c;
#pragma unroll
          for (int dt = 0; dt < 3; ++dt)
#pragma unroll
            for (int dm = 0; dm < 3; ++dm)
              s += xt[(r + dt) * 42 + mp + dm] * w1[dt * 3 + dm];
          mx = fmaxf(mx, s);
        }
        yrow[1 + mo] = fmaxf(mx, 0.f);  // relu after (pool of conv+b); relu monotone
      }
    }
  }
  __syncthreads();
  // conv2: thread (co, tq) computes 2 t x 8 m outputs
  const int co = c, tq = q;
  float acc[2][8];
#pragma unroll
  for (int tl = 0; tl < 2; ++tl)
#pragma unroll
    for (int mo = 0; mo < 8; ++mo) acc[tl][mo] = 0.f;
  for (int ci = 0; ci < 128; ++ci) {
    float w[9];
#pragma unroll
    for (int i = 0; i < 9; ++i) w[i] = W2t[i * 16384 + ci * 128 + co];
    float xv[4][10];
#pragma unroll
    for (int rr = 0; rr < 4; ++rr) {
      const float* p = &y1s[((2 * tq + rr) * 128 + ci) * 12];
      const float4 a = *(const float4*)p;
      const float4 bq = *(const float4*)(p + 4);
      const float2 cq = *(const float2*)(p + 8);
      xv[rr][0] = a.x; xv[rr][1] = a.y; xv[rr][2] = a.z; xv[rr][3] = a.w;
      xv[rr][4] = bq.x; xv[rr][5] = bq.y; xv[rr][6] = bq.z; xv[rr][7] = bq.w;
      xv[rr][8] = cq.x; xv[rr][9] = cq.y;
    }
#pragma unroll
    for (int dt = 0; dt < 3; ++dt)
#pragma unroll
      for (int dm = 0; dm < 3; ++dm) {
        const float wv = w[dt * 3 + dm];
#pragma unroll
        for (int tl = 0; tl < 2; ++tl)
#pragma unroll
          for (int mo = 0; mo < 8; ++mo)
            acc[tl][mo] += xv[tl + dt][mo + dm] * wv;
      }
  }
  const float b2c = b2[co];
#pragma unroll
  for (int tl = 0; tl < 2; ++tl) {
    const int t = t0 + 2 * tq + tl;
    float m0 = fmaxf(fmaxf(acc[tl][0], acc[tl][1]), fmaxf(acc[tl][2], acc[tl][3])) + b2c;
    float m1 = fmaxf(fmaxf(acc[tl][4], acc[tl][5]), fmaxf(acc[tl][6], acc[tl][7])) + b2c;
    y2[((b * T_ + t) * 2 + 0) * 128 + co] = fmaxf(m0, 0.f);
    y2[((b * T_ + t) * 2 + 1) * 128 + co] = fmaxf(m1, 0.f);
  }
}

// ---------------- conv3+pool2 -> feats [T][B][128] ----------------
__global__ __launch_bounds__(256) void conv3_kernel(
    const float* __restrict__ y2, const float* __restrict__ W3t, const float* __restrict__ b3,
    float* __restrict__ feats) {
  __shared__ float y2s[6 * 128 * 4];  // [row][ci][mslot 0..3 (=-1..2)]
  const int tid = threadIdx.x;
  const int t0 = blockIdx.x * 4;
  const int b = blockIdx.y;
  for (int idx = tid; idx < 768; idx += 256) {
    int row = idx / 128, ci = idx % 128;
    y2s[(row * 128 + ci) * 4 + 0] = 0.f;
    y2s[(row * 128 + ci) * 4 + 3] = 0.f;
  }
  for (int idx = tid; idx < 6 * 256; idx += 256) {
    int row = idx / 256, rem = idx % 256;
    int m = rem >> 7, ci = rem & 127;
    int t_in = t0 - 1 + row;
    float v = 0.f;
    if (t_in >= 0 && t_in < T_) v = y2[((b * T_ + t_in) * 2 + m) * 128 + ci];
    y2s[(row * 128 + ci) * 4 + 1 + m] = v;
  }
  __syncthreads();
  const int co = tid & 127, tq = tid >> 7;
  float acc[2][2] = {{0.f, 0.f}, {0.f, 0.f}};
  for (int ci = 0; ci < 128; ++ci) {
    float w[9];
#pragma unroll
    for (int i = 0; i < 9; ++i) w[i] = W3t[i * 16384 + ci * 128 + co];
    float4 xr[4];
#pragma unroll
    for (int rr = 0; rr < 4; ++rr)
      xr[rr] = *(const float4*)&y2s[((2 * tq + rr) * 128 + ci) * 4];
#pragma unroll
    for (int dt = 0; dt < 3; ++dt)
#pragma unroll
      for (int tl = 0; tl < 2; ++tl) {
        const float4 v = xr[tl + dt];
        acc[tl][0] += v.y * w[dt * 3 + 1] + v.z * w[dt * 3 + 2];  // m=0: taps dm=1,2
        acc[tl][1] += v.y * w[dt * 3 + 0] + v.z * w[dt * 3 + 1];  // m=1: taps dm=0,1
      }
  }
  const float b3c = b3[co];
#pragma unroll
  for (int tl = 0; tl < 2; ++tl) {
    const int t = t0 + 2 * tq + tl;
    float f = fmaxf(fmaxf(acc[tl][0], acc[tl][1]) + b3c, 0.f);
    feats[(t * B_ + b) * 128 + co] = f;
  }
}

// ---------------- gi_x = feats @ W_ih_x^T + b_ih -> [T*B][768] ----------------
__global__ __launch_bounds__(256) void gid_kernel(
    const float* __restrict__ feats, const float* __restrict__ WihT4,
    const float* __restrict__ b_ih, float* __restrict__ gi) {
  __shared__ float fs[32 * 128];
  const int tid = threadIdx.x;
  const int jb = blockIdx.x;  // 0..2
  const int rb = blockIdx.y;  // 0..1023
  const float4* src = (const float4*)(feats + rb * 32 * 128);
  float4* dst = (float4*)fs;
  for (int i = tid; i < 1024; i += 256) dst[i] = src[i];
  __syncthreads();
  const int j = jb * 256 + tid;
  float acc[32];
#pragma unroll
  for (int r = 0; r < 32; ++r) acc[r] = 0.f;
  for (int k4 = 0; k4 < 32; ++k4) {
    const float4 w4 = *(const float4*)&WihT4[(k4 * 768 + j) * 4];
#pragma unroll
    for (int r = 0; r < 32; ++r) {
      const float4 f4 = *(const float4*)&fs[r * 128 + k4 * 4];
      acc[r] += f4.x * w4.x + f4.y * w4.y + f4.z * w4.z + f4.w * w4.w;
    }
  }
  const float bj = b_ih[j];
  for (int r = 0; r < 32; ++r) gi[(rb * 32 + r) * 768 + j] = acc[r] + bj;
}

// ---------------- persistent GRU: 32 blocks (one batch each), 768 threads ----------------
// R3 structure, exact fp32 W_hh. On-die W caching (values unchanged, same acc order):
//   kk4 groups 0..5  -> pinned in registers (96 VGPR/thread, 295 KB/CU, free)
//   kk4 groups 6..7  -> LDS, lane-interleaved b64 layout (98.3 KB, 4-way conflicts ok)
//   kk4 groups 8..15 -> streamed from L2 (393 KB/step, was 786 KB)
__global__ __launch_bounds__(768) void rnn_kernel(
    const float* __restrict__ gi, const float* __restrict__ WhhT,
    const float* __restrict__ W_ih, const float* __restrict__ b_hh,
    const float* __restrict__ Wf, const float* __restrict__ bf,
    const float* __restrict__ targets, const int* __restrict__ force_mask,
    float* __restrict__ out) {
  __shared__ float Wl[2 * 8 * 1536];  // [gg][fp][tid*2+par]  96.0 KB
  __shared__ float h_s[256];
  __shared__ float tf_s[16];
  __shared__ float gis[768];
  __shared__ float part[4 * 768];
  __shared__ float wtf[10 * 768];
  __shared__ float wfs[10 * 256];
  __shared__ float bhh_s[768];
  __shared__ float bf_s[16];
  const int tid = threadIdx.x;
  const int b = blockIdx.x;
  for (int idx = tid; idx < 7680; idx += 768) {
    int cc = idx / 768, j = idx % 768;
    wtf[idx] = W_ih[j * 138 + 128 + cc];
  }
  for (int idx = tid; idx < 2560; idx += 768) wfs[idx] = Wf[idx];
  bhh_s[tid] = b_hh[tid];
  if (tid < 256) h_s[tid] = 0.f;
  if (tid < 10) { tf_s[tid] = 0.f; bf_s[tid] = bf[tid]; }
  const int ks = tid / 192;   // k-slice 0..3 (wave-uniform; 192%64==0)
  const int jq = tid % 192;   // j-quad
  const float* wbase = WhhT + (ks * 64) * 768 + jq * 4;
  // pin groups 0..5 in registers
  float4 wr[6][4];
#pragma unroll
  for (int g = 0; g < 6; ++g) {
    const float* wp0 = wbase + g * 3072;
    wr[g][0] = *(const float4*)(wp0);
    wr[g][1] = *(const float4*)(wp0 + 768);
    wr[g][2] = *(const float4*)(wp0 + 1536);
    wr[g][3] = *(const float4*)(wp0 + 2304);
  }
  // fill LDS W for groups 6..7: float f (0..15) = wq(f/4).comp(f%4); pairs at
  // Wl[(gg*8+fp)*1536 + tid*2 + par], f = 2*fp+par
#pragma unroll
  for (int gg = 0; gg < 2; ++gg) {
    const float* src = wbase + (6 + gg) * 3072;
#pragma unroll
    for (int fp = 0; fp < 8; ++fp) {
      const int f0 = 2 * fp, f1 = 2 * fp + 1;
      Wl[(gg * 8 + fp) * 1536 + tid * 2 + 0] = src[(f0 >> 2) * 768 + (f0 & 3)];
      Wl[(gg * 8 + fp) * 1536 + tid * 2 + 1] = src[(f1 >> 2) * 768 + (f1 & 3)];
    }
  }
  __syncthreads();
  for (int t = 0; t < T_; ++t) {
    // gi row + teacher-forcing contribution
    float giv = gi[(t * B_ + b) * 768 + tid];
#pragma unroll
    for (int cc = 0; cc < 10; ++cc) giv += wtf[cc * 768 + tid] * tf_s[cc];
    float4 a4 = make_float4(0.f, 0.f, 0.f, 0.f);
    // groups 0..5: registers
#pragma unroll
    for (int g = 0; g < 6; ++g) {
      const float4 h4 = *(const float4*)&h_s[ks * 64 + g * 4];
      a4.x += wr[g][0].x * h4.x + wr[g][1].x * h4.y + wr[g][2].x * h4.z + wr[g][3].x * h4.w;
      a4.y += wr[g][0].y * h4.x + wr[g][1].y * h4.y + wr[g][2].y * h4.z + wr[g][3].y * h4.w;
      a4.z += wr[g][0].z * h4.x + wr[g][1].z * h4.y + wr[g][2].z * h4.z + wr[g][3].z * h4.w;
      a4.w += wr[g][0].w * h4.x + wr[g][1].w * h4.y + wr[g][2].w * h4.z + wr[g][3].w * h4.w;
    }
    // groups 6..7: LDS (pairs: p0=w0.xy p1=w0.zw p2=w1.xy p3=w1.zw p4=w2.xy p5=w2.zw p6=w3.xy p7=w3.zw)
#pragma unroll
    for (int gg = 0; gg < 2; ++gg) {
      const float4 h4 = *(const float4*)&h_s[ks * 64 + (6 + gg) * 4];
      const float* base = &Wl[(gg * 8) * 1536 + tid * 2];
      const float2 p0 = *(const float2*)(base);
      const float2 p1 = *(const float2*)(base + 1536);
      const float2 p2 = *(const float2*)(base + 3072);
      const float2 p3 = *(const float2*)(base + 4608);
      const float2 p4 = *(const float2*)(base + 6144);
      const float2 p5 = *(const float2*)(base + 7680);
      const float2 p6 = *(const float2*)(base + 9216);
      const float2 p7 = *(const float2*)(base + 10752);
      a4.x += p0.x * h4.x + p2.x * h4.y + p4.x * h4.z + p6.x * h4.w;
      a4.y += p0.y * h4.x + p2.y * h4.y + p4.y * h4.z + p6.y * h4.w;
      a4.z += p1.x * h4.x + p3.x * h4.y + p5.x * h4.z + p7.x * h4.w;
      a4.w += p1.y * h4.x + p3.y * h4.y + p5.y * h4.z + p7.y * h4.w;
    }
    // groups 8..15: streamed from L2
    const float* wp = wbase + 8 * 3072;
#pragma unroll 2
    for (int g8 = 8; g8 < 16; ++g8) {
      const float4 w0 = *(const float4*)(wp);
      const float4 w1v = *(const float4*)(wp + 768);
      const float4 w2v = *(const float4*)(wp + 1536);
      const float4 w3v = *(const float4*)(wp + 2304);
      const float4 h4 = *(const float4*)&h_s[ks * 64 + g8 * 4];
      a4.x += w0.x * h4.x + w1v.x * h4.y + w2v.x * h4.z + w3v.x * h4.w;
      a4.y += w0.y * h4.x + w1v.y * h4.y + w2v.y * h4.z + w3v.y * h4.w;
      a4.z += w0.z * h4.x + w1v.z * h4.y + w2v.z * h4.z + w3v.z * h4.w;
      a4.w += w0.w * h4.x + w1v.w * h4.y + w2v.w * h4.z + w3v.w * h4.w;
      wp += 3072;
    }
    *(float4*)&part[ks * 768 + jq * 4] = a4;
    gis[tid] = giv;
    __syncthreads();
    if (tid < 256) {
      const int j = tid;
      float ghr = bhh_s[j] + part[j] + part[768 + j] + part[1536 + j] + part[2304 + j];
      float ghz = bhh_s[256 + j] + part[256 + j] + part[1024 + j] + part[1792 + j] + part[2560 + j];
      float ghn = bhh_s[512 + j] + part[512 + j] + part[1280 + j] + part[2048 + j] + part[2816 + j];
      const float r = 1.f / (1.f + expf(-(gis[j] + ghr)));
      const float z = 1.f / (1.f + expf(-(gis[256 + j] + ghz)));
      const float n = tanhf(gis[512 + j] + r * ghn);
      h_s[j] = (1.f - z) * n + z * h_s[j];
    }
    __syncthreads();
    if (tid < 64) {
      const float h0 = h_s[tid], h1 = h_s[tid + 64], h2 = h_s[tid + 128], h3 = h_s[tid + 192];
      float p[10];
#pragma unroll
      for (int cc = 0; cc < 10; ++cc)
        p[cc] = wfs[cc * 256 + tid] * h0 + wfs[cc * 256 + tid + 64] * h1 +
                wfs[cc * 256 + tid + 128] * h2 + wfs[cc * 256 + tid + 192] * h3;
#pragma unroll
      for (int off = 32; off > 0; off >>= 1)
#pragma unroll
        for (int cc = 0; cc < 10; ++cc) p[cc] += __shfl_xor(p[cc], off);
      if (tid == 0) {
        const int fm = force_mask[t * B_ + b];
#pragma unroll
        for (int cc = 0; cc < 10; ++cc) {
          const float o = p[cc] + bf_s[cc];
          out[(b * T_ + t) * 10 + cc] = o;
          tf_s[cc] = (fm > 0) ? targets[(b * T_ + t) * 10 + cc] : (o > 0.f ? 1.f : 0.f);
        }
      }
    }
    __syncthreads();
  }
}

extern "C" void kernel_launch(void* const* d_in, const int* in_sizes, int n_in,
                              void* d_out, int out_size, void* d_ws, size_t ws_size,
                              hipStream_t stream) {
  const float* x = (const float*)d_in[0];
  const float* targets = (const float*)d_in[1];
  const int* fmask = (const int*)d_in[2];
  const float* W1 = (const float*)d_in[3];
  const float* b1 = (const float*)d_in[4];
  const float* W2 = (const float*)d_in[5];
  const float* b2 = (const float*)d_in[6];
  const float* W3 = (const float*)d_in[7];
  const float* b3 = (const float*)d_in[8];
  const float* Wih = (const float*)d_in[9];
  const float* Whh = (const float*)d_in[10];
  const float* bih = (const float*)d_in[11];
  const float* bhh = (const float*)d_in[12];
  const float* Wf = (const float*)d_in[13];
  const float* bf = (const float*)d_in[14];
  float* out = (float*)d_out;
  float* ws = (float*)d_ws;
  // workspace layout (floats), peak 29,949,952 (~114.25 MiB).
  // y2 aliases gi (y2 dead after conv3, gi written after — stream-ordered, safe).
  float* WhhT = ws;                 // 196608
  float* W2t = ws + 196608;         // 147456
  float* W3t = ws + 344064;         // 147456
  float* WihT4 = ws + 491520;       // 98304
  float* feats = ws + 589824;       // 4194304
  float* gi = ws + 4784128;         // 25165824
  float* y2 = gi;                   // 8388608 (alias)

  prep_kernel<<<2304, 256, 0, stream>>>(Whh, W2, W3, Wih, WhhT, W2t, W3t, WihT4);
  conv12_kernel<<<dim3(256, 32), 256, 0, stream>>>(x, W1, b1, W2t, b2, y2);
  conv3_kernel<<<dim3(256, 32), 256, 0, stream>>>(y2, W3t, b3, feats);
  gid_kernel<<<dim3(3, 1024), 256, 0, stream>>>(feats, WihT4, bih, gi);
  rnn_kernel<<<32, 768, 0, stream>>>(gi, WhhT, Wih, bhh, Wf, bf, targets, fmask, out);
}

// Round 9
// 7231.406 us; speedup vs baseline: 1.3815x; 1.1064x over previous
//
#include <hip/hip_runtime.h>
#include <math.h>

#define B_ 32
#define T_ 1024
#define M_ 40

// ---------------- weight prep (transposes for coalesced access) ----------------
__global__ void prep_kernel(const float* __restrict__ W_hh, const float* __restrict__ W2,
                            const float* __restrict__ W3, const float* __restrict__ W_ih,
                            float* __restrict__ WhhT, float* __restrict__ W2t,
                            float* __restrict__ W3t, float* __restrict__ WihT4) {
  int idx = blockIdx.x * 256 + threadIdx.x;
  if (idx < 196608) {  // WhhT[k][j] = W_hh[j][k]
    int k = idx / 768, j = idx % 768;
    WhhT[idx] = W_hh[j * 256 + k];
    return;
  }
  idx -= 196608;
  if (idx < 147456) {  // W2t[tap][ci][co]
    int tap = idx >> 14, ci = (idx >> 7) & 127, co = idx & 127;
    W2t[idx] = W2[(co * 128 + ci) * 9 + tap];
    return;
  }
  idx -= 147456;
  if (idx < 147456) {  // W3t[tap][ci][co]
    int tap = idx >> 14, ci = (idx >> 7) & 127, co = idx & 127;
    W3t[idx] = W3[(co * 128 + ci) * 9 + tap];
    return;
  }
  idx -= 147456;
  if (idx < 98304) {  // WihT4[k/4][j][k%4] = W_ih[j][k] (x-part, k<128)
    int khi = idx / 3072, rem = idx % 3072, j = rem >> 2, klo = rem & 3;
    WihT4[idx] = W_ih[j * 138 + khi * 4 + klo];
  }
}

// ---------------- fused conv1+pool5 + conv2+pool4 ----------------
// grid (T/4, B), block 256.  y2: [B][T][2][128]
__global__ __launch_bounds__(256) void conv12_kernel(
    const float* __restrict__ x, const float* __restrict__ W1, const float* __restrict__ b1,
    const float* __restrict__ W2t, const float* __restrict__ b2, float* __restrict__ y2) {
  __shared__ float xt[8 * 42];          // x rows t0-2..t0+5, mel slots -1..40
  __shared__ float y1s[6 * 128 * 12];   // y1 rows t0-1..t0+4, [row][c][mslot 0..9 (=-1..8), pad]
  const int tid = threadIdx.x;
  const int t0 = blockIdx.x * 4;
  const int b = blockIdx.y;
  for (int idx = tid; idx < 8 * 42; idx += 256) {
    int row = idx / 42, slot = idx % 42;
    int t_in = t0 - 2 + row, m = slot - 1;
    float v = 0.f;
    if (t_in >= 0 && t_in < T_ && m >= 0 && m < M_) v = x[(b * T_ + t_in) * M_ + m];
    xt[idx] = v;
  }
  __syncthreads();
  const int c = tid & 127, q = tid >> 7;
  float w1[9];
#pragma unroll
  for (int i = 0; i < 9; ++i) w1[i] = W1[c * 9 + i];
  const float b1c = b1[c];
  for (int rr = 0; rr < 3; ++rr) {
    const int r = q * 3 + rr;
    const int t_in = t0 - 1 + r;
    float* yrow = &y1s[(r * 128 + c) * 12];
    if (t_in < 0 || t_in >= T_) {
#pragma unroll
      for (int s = 0; s < 12; ++s) yrow[s] = 0.f;
    } else {
      yrow[0] = 0.f; yrow[9] = 0.f; yrow[10] = 0.f; yrow[11] = 0.f;
#pragma unroll
      for (int mo = 0; mo < 8; ++mo) {
        float mx = -1e30f;
#pragma unroll
        for (int i5 = 0; i5 < 5; ++i5) {
          const int mp = mo * 5 + i5;
          float s = b1c;
#pragma unroll
          for (int dt = 0; dt < 3; ++dt)
#pragma unroll
            for (int dm = 0; dm < 3; ++dm)
              s += xt[(r + dt) * 42 + mp + dm] * w1[dt * 3 + dm];
          mx = fmaxf(mx, s);
        }
        yrow[1 + mo] = fmaxf(mx, 0.f);  // relu after (pool of conv+b); relu monotone
      }
    }
  }
  __syncthreads();
  // conv2: thread (co, tq) computes 2 t x 8 m outputs
  const int co = c, tq = q;
  float acc[2][8];
#pragma unroll
  for (int tl = 0; tl < 2; ++tl)
#pragma unroll
    for (int mo = 0; mo < 8; ++mo) acc[tl][mo] = 0.f;
  for (int ci = 0; ci < 128; ++ci) {
    float w[9];
#pragma unroll
    for (int i = 0; i < 9; ++i) w[i] = W2t[i * 16384 + ci * 128 + co];
    float xv[4][10];
#pragma unroll
    for (int rr = 0; rr < 4; ++rr) {
      const float* p = &y1s[((2 * tq + rr) * 128 + ci) * 12];
      const float4 a = *(const float4*)p;
      const float4 bq = *(const float4*)(p + 4);
      const float2 cq = *(const float2*)(p + 8);
      xv[rr][0] = a.x; xv[rr][1] = a.y; xv[rr][2] = a.z; xv[rr][3] = a.w;
      xv[rr][4] = bq.x; xv[rr][5] = bq.y; xv[rr][6] = bq.z; xv[rr][7] = bq.w;
      xv[rr][8] = cq.x; xv[rr][9] = cq.y;
    }
#pragma unroll
    for (int dt = 0; dt < 3; ++dt)
#pragma unroll
      for (int dm = 0; dm < 3; ++dm) {
        const float wv = w[dt * 3 + dm];
#pragma unroll
        for (int tl = 0; tl < 2; ++tl)
#pragma unroll
          for (int mo = 0; mo < 8; ++mo)
            acc[tl][mo] += xv[tl + dt][mo + dm] * wv;
      }
  }
  const float b2c = b2[co];
#pragma unroll
  for (int tl = 0; tl < 2; ++tl) {
    const int t = t0 + 2 * tq + tl;
    float m0 = fmaxf(fmaxf(acc[tl][0], acc[tl][1]), fmaxf(acc[tl][2], acc[tl][3])) + b2c;
    float m1 = fmaxf(fmaxf(acc[tl][4], acc[tl][5]), fmaxf(acc[tl][6], acc[tl][7])) + b2c;
    y2[((b * T_ + t) * 2 + 0) * 128 + co] = fmaxf(m0, 0.f);
    y2[((b * T_ + t) * 2 + 1) * 128 + co] = fmaxf(m1, 0.f);
  }
}

// ---------------- conv3+pool2 -> feats [T][B][128] ----------------
__global__ __launch_bounds__(256) void conv3_kernel(
    const float* __restrict__ y2, const float* __restrict__ W3t, const float* __restrict__ b3,
    float* __restrict__ feats) {
  __shared__ float y2s[6 * 128 * 4];  // [row][ci][mslot 0..3 (=-1..2)]
  const int tid = threadIdx.x;
  const int t0 = blockIdx.x * 4;
  const int b = blockIdx.y;
  for (int idx = tid; idx < 768; idx += 256) {
    int row = idx / 128, ci = idx % 128;
    y2s[(row * 128 + ci) * 4 + 0] = 0.f;
    y2s[(row * 128 + ci) * 4 + 3] = 0.f;
  }
  for (int idx = tid; idx < 6 * 256; idx += 256) {
    int row = idx / 256, rem = idx % 256;
    int m = rem >> 7, ci = rem & 127;
    int t_in = t0 - 1 + row;
    float v = 0.f;
    if (t_in >= 0 && t_in < T_) v = y2[((b * T_ + t_in) * 2 + m) * 128 + ci];
    y2s[(row * 128 + ci) * 4 + 1 + m] = v;
  }
  __syncthreads();
  const int co = tid & 127, tq = tid >> 7;
  float acc[2][2] = {{0.f, 0.f}, {0.f, 0.f}};
  for (int ci = 0; ci < 128; ++ci) {
    float w[9];
#pragma unroll
    for (int i = 0; i < 9; ++i) w[i] = W3t[i * 16384 + ci * 128 + co];
    float4 xr[4];
#pragma unroll
    for (int rr = 0; rr < 4; ++rr)
      xr[rr] = *(const float4*)&y2s[((2 * tq + rr) * 128 + ci) * 4];
#pragma unroll
    for (int dt = 0; dt < 3; ++dt)
#pragma unroll
      for (int tl = 0; tl < 2; ++tl) {
        const float4 v = xr[tl + dt];
        acc[tl][0] += v.y * w[dt * 3 + 1] + v.z * w[dt * 3 + 2];  // m=0: taps dm=1,2
        acc[tl][1] += v.y * w[dt * 3 + 0] + v.z * w[dt * 3 + 1];  // m=1: taps dm=0,1
      }
  }
  const float b3c = b3[co];
#pragma unroll
  for (int tl = 0; tl < 2; ++tl) {
    const int t = t0 + 2 * tq + tl;
    float f = fmaxf(fmaxf(acc[tl][0], acc[tl][1]) + b3c, 0.f);
    feats[(t * B_ + b) * 128 + co] = f;
  }
}

// ---------------- gi_x = feats @ W_ih_x^T + b_ih -> [T*B][768] ----------------
__global__ __launch_bounds__(256) void gid_kernel(
    const float* __restrict__ feats, const float* __restrict__ WihT4,
    const float* __restrict__ b_ih, float* __restrict__ gi) {
  __shared__ float fs[32 * 128];
  const int tid = threadIdx.x;
  const int jb = blockIdx.x;  // 0..2
  const int rb = blockIdx.y;  // 0..1023
  const float4* src = (const float4*)(feats + rb * 32 * 128);
  float4* dst = (float4*)fs;
  for (int i = tid; i < 1024; i += 256) dst[i] = src[i];
  __syncthreads();
  const int j = jb * 256 + tid;
  float acc[32];
#pragma unroll
  for (int r = 0; r < 32; ++r) acc[r] = 0.f;
  for (int k4 = 0; k4 < 32; ++k4) {
    const float4 w4 = *(const float4*)&WihT4[(k4 * 768 + j) * 4];
#pragma unroll
    for (int r = 0; r < 32; ++r) {
      const float4 f4 = *(const float4*)&fs[r * 128 + k4 * 4];
      acc[r] += f4.x * w4.x + f4.y * w4.y + f4.z * w4.z + f4.w * w4.w;
    }
  }
  const float bj = b_ih[j];
  for (int r = 0; r < 32; ++r) gi[(rb * 32 + r) * 768 + j] = acc[r] + bj;
}

// ---------------- persistent GRU: 32 blocks (one batch each), 768 threads ----------------
// R8 structure + two changes (arithmetic bit-identical):
//  1) __launch_bounds__(768,3): VGPR cap ~170 so the 96-VGPR W pin (groups 0..5)
//     actually sticks (R8 compiled at 84 VGPR -> pins rematerialized to L2 loads).
//  2) 2 barriers/step: tf-contribution moved into the gate phase (same fp order),
//     so matvec(t+1) no longer depends on tf_s and overlaps with out(t) on wave 0.
__global__ __launch_bounds__(768, 3) void rnn_kernel(
    const float* __restrict__ gi, const float* __restrict__ WhhT,
    const float* __restrict__ W_ih, const float* __restrict__ b_hh,
    const float* __restrict__ Wf, const float* __restrict__ bf,
    const float* __restrict__ targets, const int* __restrict__ force_mask,
    float* __restrict__ out) {
  __shared__ float Wl[2 * 8 * 1536];  // [gg][fp][tid*2+par]  96.0 KB
  __shared__ float h_s[256];
  __shared__ float tf_s[16];
  __shared__ float gis[768];
  __shared__ float part[4 * 768];
  __shared__ float wtf[10 * 768];
  __shared__ float wfs[10 * 256];
  __shared__ float bhh_s[768];
  __shared__ float bf_s[16];
  const int tid = threadIdx.x;
  const int b = blockIdx.x;
  for (int idx = tid; idx < 7680; idx += 768) {
    int cc = idx / 768, j = idx % 768;
    wtf[idx] = W_ih[j * 138 + 128 + cc];
  }
  for (int idx = tid; idx < 2560; idx += 768) wfs[idx] = Wf[idx];
  bhh_s[tid] = b_hh[tid];
  if (tid < 256) h_s[tid] = 0.f;
  if (tid < 10) { tf_s[tid] = 0.f; bf_s[tid] = bf[tid]; }
  const int ks = tid / 192;   // k-slice 0..3 (wave-uniform; 192%64==0)
  const int jq = tid % 192;   // j-quad
  const float* wbase = WhhT + (ks * 64) * 768 + jq * 4;
  // pin groups 0..5 in registers
  float4 wr[6][4];
#pragma unroll
  for (int g = 0; g < 6; ++g) {
    const float* wp0 = wbase + g * 3072;
    wr[g][0] = *(const float4*)(wp0);
    wr[g][1] = *(const float4*)(wp0 + 768);
    wr[g][2] = *(const float4*)(wp0 + 1536);
    wr[g][3] = *(const float4*)(wp0 + 2304);
  }
  // fill LDS W for groups 6..7
#pragma unroll
  for (int gg = 0; gg < 2; ++gg) {
    const float* src = wbase + (6 + gg) * 3072;
#pragma unroll
    for (int fp = 0; fp < 8; ++fp) {
      const int f0 = 2 * fp, f1 = 2 * fp + 1;
      Wl[(gg * 8 + fp) * 1536 + tid * 2 + 0] = src[(f0 >> 2) * 768 + (f0 & 3)];
      Wl[(gg * 8 + fp) * 1536 + tid * 2 + 1] = src[(f1 >> 2) * 768 + (f1 & 3)];
    }
  }
  __syncthreads();

  auto matvec = [&](int tt) {
    float giv = gi[(tt * B_ + b) * 768 + tid];
    float4 a4 = make_float4(0.f, 0.f, 0.f, 0.f);
    // groups 0..5: registers
#pragma unroll
    for (int g = 0; g < 6; ++g) {
      const float4 h4 = *(const float4*)&h_s[ks * 64 + g * 4];
      a4.x += wr[g][0].x * h4.x + wr[g][1].x * h4.y + wr[g][2].x * h4.z + wr[g][3].x * h4.w;
      a4.y += wr[g][0].y * h4.x + wr[g][1].y * h4.y + wr[g][2].y * h4.z + wr[g][3].y * h4.w;
      a4.z += wr[g][0].z * h4.x + wr[g][1].z * h4.y + wr[g][2].z * h4.z + wr[g][3].z * h4.w;
      a4.w += wr[g][0].w * h4.x + wr[g][1].w * h4.y + wr[g][2].w * h4.z + wr[g][3].w * h4.w;
    }
    // groups 6..7: LDS
#pragma unroll
    for (int gg = 0; gg < 2; ++gg) {
      const float4 h4 = *(const float4*)&h_s[ks * 64 + (6 + gg) * 4];
      const float* base = &Wl[(gg * 8) * 1536 + tid * 2];
      const float2 p0 = *(const float2*)(base);
      const float2 p1 = *(const float2*)(base + 1536);
      const float2 p2 = *(const float2*)(base + 3072);
      const float2 p3 = *(const float2*)(base + 4608);
      const float2 p4 = *(const float2*)(base + 6144);
      const float2 p5 = *(const float2*)(base + 7680);
      const float2 p6 = *(const float2*)(base + 9216);
      const float2 p7 = *(const float2*)(base + 10752);
      a4.x += p0.x * h4.x + p2.x * h4.y + p4.x * h4.z + p6.x * h4.w;
      a4.y += p0.y * h4.x + p2.y * h4.y + p4.y * h4.z + p6.y * h4.w;
      a4.z += p1.x * h4.x + p3.x * h4.y + p5.x * h4.z + p7.x * h4.w;
      a4.w += p1.y * h4.x + p3.y * h4.y + p5.y * h4.z + p7.y * h4.w;
    }
    // groups 8..15: streamed from L2
    const float* wp = wbase + 8 * 3072;
#pragma unroll 2
    for (int g8 = 8; g8 < 16; ++g8) {
      const float4 w0 = *(const float4*)(wp);
      const float4 w1v = *(const float4*)(wp + 768);
      const float4 w2v = *(const float4*)(wp + 1536);
      const float4 w3v = *(const float4*)(wp + 2304);
      const float4 h4 = *(const float4*)&h_s[ks * 64 + g8 * 4];
      a4.x += w0.x * h4.x + w1v.x * h4.y + w2v.x * h4.z + w3v.x * h4.w;
      a4.y += w0.y * h4.x + w1v.y * h4.y + w2v.y * h4.z + w3v.y * h4.w;
      a4.z += w0.z * h4.x + w1v.z * h4.y + w2v.z * h4.z + w3v.z * h4.w;
      a4.w += w0.w * h4.x + w1v.w * h4.y + w2v.w * h4.z + w3v.w * h4.w;
      wp += 3072;
    }
    *(float4*)&part[ks * 768 + jq * 4] = a4;
    gis[tid] = giv;
  };

  // one-step-ahead prefetch of force_mask/targets (tid 0 only)
  int fm_r = 0;
  float tg_r[10];
  if (tid == 0) {
    fm_r = force_mask[0 * B_ + b];
#pragma unroll
    for (int cc = 0; cc < 10; ++cc) tg_r[cc] = targets[(b * T_ + 0) * 10 + cc];
  }
  matvec(0);
  __syncthreads();  // S1: part(0), gis(0) ready

  for (int t = 0; t < T_; ++t) {
    // gate phase (tid<256): gh sums + tf contribution (same fp order as R3/R8)
    if (tid < 256) {
      const int j = tid;
      float gr = gis[j], gz = gis[256 + j], gn0 = gis[512 + j];
#pragma unroll
      for (int cc = 0; cc < 10; ++cc) {
        const float tfv = tf_s[cc];
        gr += wtf[cc * 768 + j] * tfv;
        gz += wtf[cc * 768 + 256 + j] * tfv;
        gn0 += wtf[cc * 768 + 512 + j] * tfv;
      }
      float ghr = bhh_s[j] + part[j] + part[768 + j] + part[1536 + j] + part[2304 + j];
      float ghz = bhh_s[256 + j] + part[256 + j] + part[1024 + j] + part[1792 + j] + part[2560 + j];
      float ghn = bhh_s[512 + j] + part[512 + j] + part[1280 + j] + part[2048 + j] + part[2816 + j];
      const float r = 1.f / (1.f + expf(-(gr + ghr)));
      const float z = 1.f / (1.f + expf(-(gz + ghz)));
      const float n = tanhf(gn0 + r * ghn);
      h_s[j] = (1.f - z) * n + z * h_s[j];
    }
    __syncthreads();  // S2: h(t) ready
    // out(t) on wave 0 + matvec(t+1) on all waves (both only READ h_s)
    if (tid < 64) {
      const float h0 = h_s[tid], h1 = h_s[tid + 64], h2 = h_s[tid + 128], h3 = h_s[tid + 192];
      float p[10];
#pragma unroll
      for (int cc = 0; cc < 10; ++cc)
        p[cc] = wfs[cc * 256 + tid] * h0 + wfs[cc * 256 + tid + 64] * h1 +
                wfs[cc * 256 + tid + 128] * h2 + wfs[cc * 256 + tid + 192] * h3;
#pragma unroll
      for (int off = 32; off > 0; off >>= 1)
#pragma unroll
        for (int cc = 0; cc < 10; ++cc) p[cc] += __shfl_xor(p[cc], off);
      if (tid == 0) {
#pragma unroll
        for (int cc = 0; cc < 10; ++cc) {
          const float o = p[cc] + bf_s[cc];
          out[(b * T_ + t) * 10 + cc] = o;
          tf_s[cc] = (fm_r > 0) ? tg_r[cc] : (o > 0.f ? 1.f : 0.f);
        }
        if (t + 1 < T_) {  // prefetch next step's fm/targets
          fm_r = force_mask[(t + 1) * B_ + b];
#pragma unroll
          for (int cc = 0; cc < 10; ++cc) tg_r[cc] = targets[(b * T_ + t + 1) * 10 + cc];
        }
      }
    }
    if (t + 1 < T_) matvec(t + 1);
    __syncthreads();  // S1 for next iter: part/gis/tf_s ready
  }
}

extern "C" void kernel_launch(void* const* d_in, const int* in_sizes, int n_in,
                              void* d_out, int out_size, void* d_ws, size_t ws_size,
                              hipStream_t stream) {
  const float* x = (const float*)d_in[0];
  const float* targets = (const float*)d_in[1];
  const int* fmask = (const int*)d_in[2];
  const float* W1 = (const float*)d_in[3];
  const float* b1 = (const float*)d_in[4];
  const float* W2 = (const float*)d_in[5];
  const float* b2 = (const float*)d_in[6];
  const float* W3 = (const float*)d_in[7];
  const float* b3 = (const float*)d_in[8];
  const float* Wih = (const float*)d_in[9];
  const float* Whh = (const float*)d_in[10];
  const float* bih = (const float*)d_in[11];
  const float* bhh = (const float*)d_in[12];
  const float* Wf = (const float*)d_in[13];
  const float* bf = (const float*)d_in[14];
  float* out = (float*)d_out;
  float* ws = (float*)d_ws;
  // workspace layout (floats), peak 29,949,952 (~114.25 MiB).
  // y2 aliases gi (y2 dead after conv3, gi written after — stream-ordered, safe).
  float* WhhT = ws;                 // 196608
  float* W2t = ws + 196608;         // 147456
  float* W3t = ws + 344064;         // 147456
  float* WihT4 = ws + 491520;       // 98304
  float* feats = ws + 589824;       // 4194304
  float* gi = ws + 4784128;         // 25165824
  float* y2 = gi;                   // 8388608 (alias)

  prep_kernel<<<2304, 256, 0, stream>>>(Whh, W2, W3, Wih, WhhT, W2t, W3t, WihT4);
  conv12_kernel<<<dim3(256, 32), 256, 0, stream>>>(x, W1, b1, W2t, b2, y2);
  conv3_kernel<<<dim3(256, 32), 256, 0, stream>>>(y2, W3t, b3, feats);
  gid_kernel<<<dim3(3, 1024), 256, 0, stream>>>(feats, WihT4, bih, gi);
  rnn_kernel<<<32, 768, 0, stream>>>(gi, WhhT, Wih, bhh, Wf, bf, targets, fmask, out);
}